// Round 1
// baseline (528.832 us; speedup 1.0000x reference)
//
#include <hip/hip_runtime.h>
#include <hip/hip_bf16.h>

// ESA_SMILES fused pipeline for MI355X (gfx950).
// Identity: cap = LN(x)@W1^T+b1 ; feat = cap@W2^T+b2 = LN(x)@(W2W1)^T+(W2b1+b2)
// out[b,d] = sum_n exp(feat[n,d])*cap[n,d] / sum_n exp(feat[n,d])
//
// R6 change (latency-bound fix, register-wall diagnosis):
//  - per-group GEMM tile shrunk 64x32 -> 64x16 (acc 64 -> 32 regs, 4 groups)
//    freeing ~32 VGPRs inside the same 128-reg/4-wave budget; B traffic per
//    block unchanged (each col-matrix still loaded once).
//  - persistent blocks: grid = 512 (2/CU), dynamic work counter in ws; each
//    block loops over entries. Next entry's x rows (group 0) prefetched into
//    the freed registers during the current entry's GEMM phase -> the ~900cy
//    HBM latency of phase-1 loads is hidden under ~5K cycles of MFMA work.
//  - epilogue masking is per-mt wave-uniform: full entries (valid==64, ~94%)
//    take a compare-free path; fully-padded mt tiles skip exp entirely.

typedef short short8 __attribute__((ext_vector_type(8)));   // 8 x bf16
typedef short short4v __attribute__((ext_vector_type(4)));
typedef float f32x4 __attribute__((ext_vector_type(4)));

__device__ inline short f2bf(float f) {
    unsigned u = __float_as_uint(f);
    u += 0x7fffu + ((u >> 16) & 1u);     // round-to-nearest-even
    return (short)(u >> 16);
}

// packed offset for element (n, k) of a 512x512 weight matrix
__device__ inline size_t packed_off(int n, int k) {
    const int t = n >> 4, l16n = n & 15;
    const int k0 = k >> 5, quad = (k >> 3) & 3, j = k & 7;
    return ((size_t)((t * 16 + k0) * 64 + quad * 16 + l16n)) * 8 + j;
}

// ---------------------------------------------------------------------------
// prep_all: ONE dispatch, role-split blocks (512 threads each):
//   blocks 0..63    : W12p = bf16(W2) @ bf16(W1) via MFMA -> packed layout
//   blocks 64..191  : W1 fp32 -> bf16, packed layout (W1p)
//   blocks 192..195 : b12 = W2@b1 + b2 (4 blocks x 128 rows, 4 thr/row)
//   block  196      : entries (binary search) + ctrl = {work_ctr=0, total}
//   blocks 197..228 : zero num/den
// ---------------------------------------------------------------------------
#define PREP_GRID 229

__global__ __launch_bounds__(512)
void esa_prep_all(const float* __restrict__ W1, const float* __restrict__ W2,
                  const float* __restrict__ b1, const float* __restrict__ b2,
                  const int* __restrict__ db, int T, int B,
                  short* __restrict__ W1p, short* __restrict__ W12p,
                  float* __restrict__ b12, int4* __restrict__ entries, int maxent,
                  float* __restrict__ numden, int* __restrict__ ctrl) {
    __shared__ int off[513];
    __shared__ int nch[512];
    __shared__ int scan[513];
    const int bid = blockIdx.x;
    const int tid = threadIdx.x;

    if (bid < 64) {
        // ---- W12 tile (64x64) via MFMA, converting fp32->bf16 on the fly
        const int ti = bid >> 3, tj = bid & 7;
        const int wave = tid >> 6;          // 0..7
        const int lane = tid & 63;
        const int quad = lane >> 4;
        const int l16 = lane & 15;
        const int mhalf = wave >> 2;        // rows half (m-tiles 0-1 or 2-3)
        const int kq = wave & 3;
        const int kcol = tj * 64 + kq * 16 + l16;

        f32x4 acc[2];
        acc[0] = (f32x4)0.0f; acc[1] = (f32x4)0.0f;
        for (int j0 = 0; j0 < 512; j0 += 32) {
            short8 bfr;
#pragma unroll
            for (int jj = 0; jj < 8; ++jj)
                bfr[jj] = f2bf(W1[(size_t)(j0 + quad * 8 + jj) * 512 + kcol]);
#pragma unroll
            for (int mt = 0; mt < 2; ++mt) {
                const float* ar = W2 + (size_t)(ti * 64 + (mhalf * 2 + mt) * 16 + l16) * 512 +
                                  j0 + quad * 8;
                const float4 a0 = *(const float4*)ar;
                const float4 a1 = *(const float4*)(ar + 4);
                short8 afr = {f2bf(a0.x), f2bf(a0.y), f2bf(a0.z), f2bf(a0.w),
                              f2bf(a1.x), f2bf(a1.y), f2bf(a1.z), f2bf(a1.w)};
                acc[mt] = __builtin_amdgcn_mfma_f32_16x16x32_bf16(afr, bfr,
                                                                  acc[mt], 0, 0, 0);
            }
        }
        // C/D layout: col(k) = lane&15, row(n) = quad*4 + r -> packed store
#pragma unroll
        for (int mt = 0; mt < 2; ++mt)
#pragma unroll
            for (int r = 0; r < 4; ++r) {
                const int n = ti * 64 + (mhalf * 2 + mt) * 16 + quad * 4 + r;
                W12p[packed_off(n, kcol)] = f2bf(acc[mt][r]);
            }
    } else if (bid < 192) {
        // ---- W1 -> bf16, packed. 4 consecutive k share a packed short4 slot.
        const int gid = (bid - 64) * 512 + tid;
        const int i4 = gid * 4;
        const int n = i4 >> 9, k = i4 & 511;
        const float4 a = *(const float4*)(W1 + i4);
        short4v sa = {f2bf(a.x), f2bf(a.y), f2bf(a.z), f2bf(a.w)};
        *(short4v*)(W1p + packed_off(n, k)) = sa;
    } else if (bid < 196) {
        // ---- b12 = W2@b1 + b2 : 4 blocks x 128 rows, 4 threads per row
        const int row = (bid - 192) * 128 + (tid >> 2);
        const int part = tid & 3;
        const float* wr = W2 + (size_t)row * 512;
        float acc = 0.0f;
#pragma unroll 4
        for (int i = 0; i < 32; ++i) {
            const float4 w = *(const float4*)(wr + (i * 4 + part) * 4);
            const float4 bb = *(const float4*)(b1 + (i * 4 + part) * 4);
            acc += w.x * bb.x + w.y * bb.y + w.z * bb.z + w.w * bb.w;
        }
        acc += __shfl_xor(acc, 1);
        acc += __shfl_xor(acc, 2);
        if (part == 0) b12[row] = acc + b2[row];
    } else if (bid == 196) {
        // ---- entries + ctrl
        for (int t = tid; t <= B; t += 512) {
            if (t == B) {
                off[t] = T;
            } else {
                int lo = 0, hi = T;
                while (lo < hi) {
                    int mid = (lo + hi) >> 1;
                    if (db[mid] < t) lo = mid + 1; else hi = mid;
                }
                off[t] = lo;
            }
        }
        __syncthreads();
        for (int t = tid; t < B; t += 512)
            nch[t] = (off[t + 1] - off[t] + 63) >> 6;
        __syncthreads();
        if (tid == 0) {
            int s = 0;
            for (int i = 0; i < B; ++i) { scan[i] = s; s += nch[i]; }
            scan[B] = s;
            ctrl[0] = 0;      // dynamic work counter
            ctrl[1] = s;      // total number of real entries
        }
        __syncthreads();
        for (int t = tid; t < B; t += 512) {
            int cnt = off[t + 1] - off[t];
            for (int j = 0; j < nch[t]; ++j) {
                int v = cnt - j * 64;
                if (v > 64) v = 64;
                entries[scan[t] + j] = make_int4(t, off[t] + j * 64, v, 0);
            }
        }
        int total = scan[B];
        for (int i = total + tid; i < maxent; i += 512)
            entries[i] = make_int4(0, 0, 0, 0);
    } else {
        // ---- zero num/den (2*B*512 floats = 131072)
        const int idx = (bid - 197) * 512 + tid;   // 0..16383
        float4 z = {0.0f, 0.0f, 0.0f, 0.0f};
        *(float4*)(numden + (size_t)idx * 8) = z;
        *(float4*)(numden + (size_t)idx * 8 + 4) = z;
    }
}

// ---------------------------------------------------------------------------
// Main fused kernel: PERSISTENT blocks (grid = 512 = 2/CU, 64 KB LDS each),
// dynamic entry counter. Per entry:
//   phase 1: LayerNorm (group 0 rows arrive via cross-entry prefetch; group 1
//            issued at loop head), XOR-swizzled LDS store.
//   phase 2: dual GEMM, wave owns 4 groups of 16 cols (acc 32 regs/group);
//            next entry's group-0 x rows prefetched under this phase.
//   epilogue per group: e=exp(feat); per-column sum(e), sum(e*cap); atomics.
// ---------------------------------------------------------------------------
__global__ __launch_bounds__(512, 4)
void esa_fused(const float* __restrict__ x, const float* __restrict__ gamma,
               const float* __restrict__ beta, const short* __restrict__ W1p,
               const short* __restrict__ W12p, const float* __restrict__ b1,
               const float* __restrict__ b12, const int4* __restrict__ entries,
               int* __restrict__ ctrl, float* __restrict__ num,
               float* __restrict__ den) {
    __shared__ short ylds[64 * 512];   // 65,536 B -> 2 blocks/CU
    __shared__ int4 ebuf[2];           // double-buffered entry broadcast
    __shared__ int eidx[2];

    const int tid = threadIdx.x;
    const int wave = tid >> 6;          // 0..7
    const int lane = tid & 63;
    const int quad = lane >> 4;
    const int l16 = lane & 15;
    const int total = ctrl[1];

    // ---- prologue: fetch first entry (slot 0)
    if (tid == 0) {
        const int j = atomicAdd(ctrl, 1);
        eidx[0] = j;
        ebuf[0] = entries[j < total ? j : total - 1];
    }
    __syncthreads();
    if (eidx[0] >= total) return;
    int4 ec = ebuf[0];
    int bat = ec.x, start = ec.y, valid = ec.z;

    float4 ra0[4], rb0[4], ra1[4], rb1[4];
    // prefetch group-0 rows of the first entry
#pragma unroll
    for (int r = 0; r < 4; ++r) {
        const int m = wave * 8 + r;
        const int mc = m < valid ? m : valid - 1;
        const float* xr = x + (size_t)(start + mc) * 512 + lane * 8;
        ra0[r] = *(const float4*)xr;
        rb0[r] = *(const float4*)(xr + 4);
    }

    const int xr7 = l16 & 7;
    const short* abase = ylds + l16 * 512;
    int p = 0;

    for (;;) {
        // -- 1. issue group-1 x loads for the current entry (hide under LN g0)
#pragma unroll
        for (int r = 0; r < 4; ++r) {
            const int m = wave * 8 + 4 + r;
            const int mc = m < valid ? m : valid - 1;
            const float* xr = x + (size_t)(start + mc) * 512 + lane * 8;
            ra1[r] = *(const float4*)xr;
            rb1[r] = *(const float4*)(xr + 4);
        }
        const float4 g0 = *(const float4*)(gamma + lane * 8);
        const float4 g1 = *(const float4*)(gamma + lane * 8 + 4);
        const float4 be0 = *(const float4*)(beta + lane * 8);
        const float4 be1 = *(const float4*)(beta + lane * 8 + 4);

        auto lnpack = [&](const float4* A, const float4* Bv, short8* ov) {
            float s[4], ss[4];
#pragma unroll
            for (int r = 0; r < 4; ++r) {
                s[r] = A[r].x + A[r].y + A[r].z + A[r].w +
                       Bv[r].x + Bv[r].y + Bv[r].z + Bv[r].w;
                ss[r] = A[r].x * A[r].x + A[r].y * A[r].y + A[r].z * A[r].z +
                        A[r].w * A[r].w + Bv[r].x * Bv[r].x + Bv[r].y * Bv[r].y +
                        Bv[r].z * Bv[r].z + Bv[r].w * Bv[r].w;
            }
#pragma unroll
            for (int o = 1; o <= 32; o <<= 1) {   // 4 interleaved chains
#pragma unroll
                for (int r = 0; r < 4; ++r) {
                    s[r] += __shfl_xor(s[r], o);
                    ss[r] += __shfl_xor(ss[r], o);
                }
            }
#pragma unroll
            for (int r = 0; r < 4; ++r) {
                const float mu = s[r] * (1.0f / 512.0f);
                const float var = ss[r] * (1.0f / 512.0f) - mu * mu;
                const float rstd = rsqrtf(var + 1e-5f);
                short8 o8;
                o8[0] = f2bf((A[r].x - mu) * rstd * g0.x + be0.x);
                o8[1] = f2bf((A[r].y - mu) * rstd * g0.y + be0.y);
                o8[2] = f2bf((A[r].z - mu) * rstd * g0.z + be0.z);
                o8[3] = f2bf((A[r].w - mu) * rstd * g0.w + be0.w);
                o8[4] = f2bf((Bv[r].x - mu) * rstd * g1.x + be1.x);
                o8[5] = f2bf((Bv[r].y - mu) * rstd * g1.y + be1.y);
                o8[6] = f2bf((Bv[r].z - mu) * rstd * g1.z + be1.z);
                o8[7] = f2bf((Bv[r].w - mu) * rstd * g1.w + be1.w);
                ov[r] = o8;
            }
        };

        // -- 2. LN group 0 (register-only; overlaps other waves' phase-2 tail)
        short8 ov0[4];
        lnpack(ra0, rb0, ov0);

        // -- 3. tid0 fetches the NEXT entry into the other slot
        if (tid == 0) {
            const int j = atomicAdd(ctrl, 1);
            eidx[p ^ 1] = j;
            ebuf[p ^ 1] = entries[j < total ? j : total - 1];
        }
        // -- 4. barrier: previous phase-2 LDS reads done; next slot published
        __syncthreads();
        // -- 5. store group-0 rows (XOR swizzle: block lane stored at lane^(m&7))
#pragma unroll
        for (int r = 0; r < 4; ++r) {
            const int m = wave * 8 + r;
            *(short8*)&ylds[m * 512 + ((lane ^ (m & 7)) * 8)] = ov0[r];
        }
        // -- 6. read next entry; issue its group-0 x prefetch (hides under GEMM)
        const int jn = eidx[p ^ 1];
        const int4 en = ebuf[p ^ 1];
        const bool have2 = (jn < total);
        if (have2) {
#pragma unroll
            for (int r = 0; r < 4; ++r) {
                const int m = wave * 8 + r;
                const int mc = m < en.z ? m : en.z - 1;
                const float* xr = x + (size_t)(en.y + mc) * 512 + lane * 8;
                ra0[r] = *(const float4*)xr;
                rb0[r] = *(const float4*)(xr + 4);
            }
        }
        // -- 7./8. LN group 1 + store
        short8 ov1[4];
        lnpack(ra1, rb1, ov1);
#pragma unroll
        for (int r = 0; r < 4; ++r) {
            const int m = wave * 8 + 4 + r;
            *(short8*)&ylds[m * 512 + ((lane ^ (m & 7)) * 8)] = ov1[r];
        }
        // -- 9. barrier: y tile complete
        __syncthreads();

        // -- 10. phase 2: 4 groups of 16 cols; acc 32 regs/group
#pragma unroll 1
        for (int grp = 0; grp < 4; ++grp) {
            const int ntile = wave * 4 + grp;
            const short* w1 = W1p + (size_t)ntile * 8192 + lane * 8;
            const short* w2 = W12p + (size_t)ntile * 8192 + lane * 8;
            f32x4 acc_c[4], acc_f[4];
#pragma unroll
            for (int mt = 0; mt < 4; ++mt) {
                acc_c[mt] = (f32x4)0.0f;
                acc_f[mt] = (f32x4)0.0f;
            }
#pragma unroll 2
            for (int k0 = 0; k0 < 16; ++k0) {
                const int blk = ((k0 << 2) | quad) ^ xr7;    // swizzled A block
                const short* ap = abase + blk * 8;
                const short8 bc = *(const short8*)(w1 + k0 * 512);
                const short8 bf = *(const short8*)(w2 + k0 * 512);
                short8 afr[4];
#pragma unroll
                for (int mt = 0; mt < 4; ++mt)
                    afr[mt] = *(const short8*)(ap + mt * 16 * 512);
#pragma unroll
                for (int mt = 0; mt < 4; ++mt) {
                    acc_c[mt] = __builtin_amdgcn_mfma_f32_16x16x32_bf16(
                        afr[mt], bc, acc_c[mt], 0, 0, 0);
                    acc_f[mt] = __builtin_amdgcn_mfma_f32_16x16x32_bf16(
                        afr[mt], bf, acc_f[mt], 0, 0, 0);
                }
            }
            // Epilogue: C/D layout col=lane&15, row=quad*4+reg (m89-verified)
            const int n = wave * 64 + grp * 16 + l16;
            const float bb1 = b1[n];
            const float bb2 = b12[n];
            float se = 0.0f, sec = 0.0f;
#pragma unroll
            for (int mt = 0; mt < 4; ++mt) {
                if ((mt + 1) * 16 <= valid) {            // wave-uniform: full tile
#pragma unroll
                    for (int r2 = 0; r2 < 4; ++r2) {
                        const float cap = acc_c[mt][r2] + bb1;
                        const float ev = __expf(acc_f[mt][r2] + bb2);
                        se += ev;
                        sec += ev * cap;
                    }
                } else if (mt * 16 < valid) {            // wave-uniform: edge tile
#pragma unroll
                    for (int r2 = 0; r2 < 4; ++r2) {
                        const int m = mt * 16 + quad * 4 + r2;
                        if (m < valid) {
                            const float cap = acc_c[mt][r2] + bb1;
                            const float ev = __expf(acc_f[mt][r2] + bb2);
                            se += ev;
                            sec += ev * cap;
                        }
                    }
                }   // else: fully padded tile, skip
            }
            se += __shfl_xor(se, 16);
            se += __shfl_xor(se, 32);
            sec += __shfl_xor(sec, 16);
            sec += __shfl_xor(sec, 32);
            if (quad == 0) atomicAdd(&den[(size_t)bat * 512 + n], se);
            else if (quad == 1) atomicAdd(&num[(size_t)bat * 512 + n], sec);
        }

        // -- 11. advance to prefetched entry
        bat = en.x; start = en.y; valid = en.z;
        p ^= 1;
        if (!have2) break;
    }
}

__global__ __launch_bounds__(256)
void esa_finalize(const float* __restrict__ num, const float* __restrict__ den,
                  float* __restrict__ out, int n) {
    const int i = blockIdx.x * 256 + threadIdx.x;
    if (i < n) {
        const float d = den[i];
        out[i] = d > 0.0f ? num[i] / d : 0.0f;
    }
}

extern "C" void kernel_launch(void* const* d_in, const int* in_sizes, int n_in,
                              void* d_out, int out_size, void* d_ws, size_t ws_size,
                              hipStream_t stream) {
    const float* x = (const float*)d_in[0];
    const int* db = (const int*)d_in[1];
    // d_in[2] = max_nodes (unused: chunking derived from actual counts)
    const float* gamma = (const float*)d_in[3];
    const float* beta = (const float*)d_in[4];
    const float* W1 = (const float*)d_in[5];
    const float* b1 = (const float*)d_in[6];
    const float* W2 = (const float*)d_in[7];
    const float* b2 = (const float*)d_in[8];
    float* out = (float*)d_out;

    const int C = in_sizes[3];        // 512
    const int D = in_sizes[6];        // 512
    const int T = in_sizes[0] / C;    // 131072
    const int B = out_size / D;       // 128
    const int maxent = B + (T + 63) / 64;   // 2176

    char* ws = (char*)d_ws;
    short* W1p = (short*)(ws);                      // 512 KB packed
    short* W12p = (short*)(ws + 524288);            // 512 KB packed
    float* b12 = (float*)(ws + 1048576);            // 2 KB
    int4* entries = (int4*)(ws + 1050624);          // maxent*16
    int* ctrl = (int*)(ws + 1050624 + (size_t)maxent * 16);   // 8 B
    size_t numoff = (1050624 + (size_t)maxent * 16 + 8 + 255) & ~(size_t)255;
    float* num = (float*)(ws + numoff);             // B*D*4
    float* den = (float*)(ws + numoff + (size_t)B * D * 4);

    esa_prep_all<<<PREP_GRID, 512, 0, stream>>>(W1, W2, b1, b2, db, T, B,
                                                W1p, W12p, b12, entries, maxent,
                                                num, ctrl);
    esa_fused<<<512, 512, 0, stream>>>(x, gamma, beta, W1p, W12p, b1, b12,
                                       entries, ctrl, num, den);
    esa_finalize<<<(B * D + 255) / 256, 256, 0, stream>>>(num, den, out, B * D);
}

// Round 2
// 469.904 us; speedup vs baseline: 1.1254x; 1.1254x over previous
//
#include <hip/hip_runtime.h>
#include <hip/hip_bf16.h>

// ESA_SMILES fused pipeline for MI355X (gfx950).
// Identity: cap = LN(x)@W1^T+b1 ; feat = cap@W2^T+b2 = LN(x)@(W2W1)^T+(W2b1+b2)
// out[b,d] = sum_n exp(feat[n,d])*cap[n,d] / sum_n exp(feat[n,d])
//
// R7 = R5 base + surgical k0-loop software pipeline.
//  - R6 post-mortem: persistent-block x-prefetch spilled (WRITE_SIZE 8.4->70MB)
//    and grp=4 doubled LDS traffic into the ~85B/cy ds_read_b128 wall.
//  - R7 keeps R5's structure exactly (grid=maxent, grp=2, 2 blocks/CU) and
//    only re-schedules the inner loop: B-fragments (L2, ~250-300cy) are
//    rolled ONE k0 ahead (+16 VGPR), paid for by streaming A-frags per-mt
//    (live 4-8 regs instead of 16). Peak live ~116 < 128 budget -> no spill.
//  - epilogue: wave-uniform valid==full fast path (no per-element compares
//    for ~94% of entries); s_setprio(1) around MFMA cluster (waves de-phased
//    in phase 2 -> T5's favorable regime).

typedef short short8 __attribute__((ext_vector_type(8)));   // 8 x bf16
typedef short short4v __attribute__((ext_vector_type(4)));
typedef float f32x4 __attribute__((ext_vector_type(4)));

__device__ inline short f2bf(float f) {
    unsigned u = __float_as_uint(f);
    u += 0x7fffu + ((u >> 16) & 1u);     // round-to-nearest-even
    return (short)(u >> 16);
}

// packed offset for element (n, k) of a 512x512 weight matrix
__device__ inline size_t packed_off(int n, int k) {
    const int t = n >> 4, l16n = n & 15;
    const int k0 = k >> 5, quad = (k >> 3) & 3, j = k & 7;
    return ((size_t)((t * 16 + k0) * 64 + quad * 16 + l16n)) * 8 + j;
}

// ---------------------------------------------------------------------------
// prep_all: ONE dispatch, role-split blocks (512 threads each):
//   blocks 0..63    : W12p = bf16(W2) @ bf16(W1) via MFMA -> packed layout
//   blocks 64..191  : W1 fp32 -> bf16, packed layout (W1p)
//   blocks 192..195 : b12 = W2@b1 + b2 (4 blocks x 128 rows, 4 thr/row)
//   block  196      : entries (binary search on sorted data_batch)
//   blocks 197..228 : zero num/den
// ---------------------------------------------------------------------------
#define PREP_GRID 229

__global__ __launch_bounds__(512)
void esa_prep_all(const float* __restrict__ W1, const float* __restrict__ W2,
                  const float* __restrict__ b1, const float* __restrict__ b2,
                  const int* __restrict__ db, int T, int B,
                  short* __restrict__ W1p, short* __restrict__ W12p,
                  float* __restrict__ b12, int4* __restrict__ entries, int maxent,
                  float* __restrict__ numden) {
    __shared__ int off[513];
    __shared__ int nch[512];
    __shared__ int scan[513];
    const int bid = blockIdx.x;
    const int tid = threadIdx.x;

    if (bid < 64) {
        // ---- W12 tile (64x64) via MFMA, converting fp32->bf16 on the fly
        const int ti = bid >> 3, tj = bid & 7;
        const int wave = tid >> 6;          // 0..7
        const int lane = tid & 63;
        const int quad = lane >> 4;
        const int l16 = lane & 15;
        const int mhalf = wave >> 2;        // rows half (m-tiles 0-1 or 2-3)
        const int kq = wave & 3;
        const int kcol = tj * 64 + kq * 16 + l16;

        f32x4 acc[2];
        acc[0] = (f32x4)0.0f; acc[1] = (f32x4)0.0f;
        for (int j0 = 0; j0 < 512; j0 += 32) {
            short8 bfr;
#pragma unroll
            for (int jj = 0; jj < 8; ++jj)
                bfr[jj] = f2bf(W1[(size_t)(j0 + quad * 8 + jj) * 512 + kcol]);
#pragma unroll
            for (int mt = 0; mt < 2; ++mt) {
                const float* ar = W2 + (size_t)(ti * 64 + (mhalf * 2 + mt) * 16 + l16) * 512 +
                                  j0 + quad * 8;
                const float4 a0 = *(const float4*)ar;
                const float4 a1 = *(const float4*)(ar + 4);
                short8 afr = {f2bf(a0.x), f2bf(a0.y), f2bf(a0.z), f2bf(a0.w),
                              f2bf(a1.x), f2bf(a1.y), f2bf(a1.z), f2bf(a1.w)};
                acc[mt] = __builtin_amdgcn_mfma_f32_16x16x32_bf16(afr, bfr,
                                                                  acc[mt], 0, 0, 0);
            }
        }
        // C/D layout: col(k) = lane&15, row(n) = quad*4 + r -> packed store
#pragma unroll
        for (int mt = 0; mt < 2; ++mt)
#pragma unroll
            for (int r = 0; r < 4; ++r) {
                const int n = ti * 64 + (mhalf * 2 + mt) * 16 + quad * 4 + r;
                W12p[packed_off(n, kcol)] = f2bf(acc[mt][r]);
            }
    } else if (bid < 192) {
        // ---- W1 -> bf16, packed. 4 consecutive k share a packed short4 slot.
        const int gid = (bid - 64) * 512 + tid;
        const int i4 = gid * 4;
        const int n = i4 >> 9, k = i4 & 511;
        const float4 a = *(const float4*)(W1 + i4);
        short4v sa = {f2bf(a.x), f2bf(a.y), f2bf(a.z), f2bf(a.w)};
        *(short4v*)(W1p + packed_off(n, k)) = sa;
    } else if (bid < 196) {
        // ---- b12 = W2@b1 + b2 : 4 blocks x 128 rows, 4 threads per row
        const int row = (bid - 192) * 128 + (tid >> 2);
        const int part = tid & 3;
        const float* wr = W2 + (size_t)row * 512;
        float acc = 0.0f;
#pragma unroll 4
        for (int i = 0; i < 32; ++i) {
            const float4 w = *(const float4*)(wr + (i * 4 + part) * 4);
            const float4 bb = *(const float4*)(b1 + (i * 4 + part) * 4);
            acc += w.x * bb.x + w.y * bb.y + w.z * bb.z + w.w * bb.w;
        }
        acc += __shfl_xor(acc, 1);
        acc += __shfl_xor(acc, 2);
        if (part == 0) b12[row] = acc + b2[row];
    } else if (bid == 196) {
        // ---- entries
        for (int t = tid; t <= B; t += 512) {
            if (t == B) {
                off[t] = T;
            } else {
                int lo = 0, hi = T;
                while (lo < hi) {
                    int mid = (lo + hi) >> 1;
                    if (db[mid] < t) lo = mid + 1; else hi = mid;
                }
                off[t] = lo;
            }
        }
        __syncthreads();
        for (int t = tid; t < B; t += 512)
            nch[t] = (off[t + 1] - off[t] + 63) >> 6;
        __syncthreads();
        if (tid == 0) {
            int s = 0;
            for (int i = 0; i < B; ++i) { scan[i] = s; s += nch[i]; }
            scan[B] = s;
        }
        __syncthreads();
        for (int t = tid; t < B; t += 512) {
            int cnt = off[t + 1] - off[t];
            for (int j = 0; j < nch[t]; ++j) {
                int v = cnt - j * 64;
                if (v > 64) v = 64;
                entries[scan[t] + j] = make_int4(t, off[t] + j * 64, v, 0);
            }
        }
        int total = scan[B];
        for (int i = total + tid; i < maxent; i += 512)
            entries[i] = make_int4(0, 0, 0, 0);
    } else {
        // ---- zero num/den (2*B*512 floats = 131072)
        const int idx = (bid - 197) * 512 + tid;   // 0..16383
        float4 z = {0.0f, 0.0f, 0.0f, 0.0f};
        *(float4*)(numden + (size_t)idx * 8) = z;
        *(float4*)(numden + (size_t)idx * 8 + 4) = z;
    }
}

// ---------------------------------------------------------------------------
// Main fused kernel: one block = 64 nodes of one batch, 512 threads (8 waves),
// 2 blocks/CU (LDS exactly 64KB) -> 16 waves/CU.
// Phase 1: LayerNorm, branch-free, 4-row ILP groups, XOR-swizzled LDS store.
// Phase 2: dual GEMM; wave owns 64 cols; A-frags streamed per-mt from
//   swizzled LDS (ds_read_b128); B-frags from PACKED layout, software-
//   pipelined ONE k0 ahead (rolling registers) so the ~250-300cy L2 latency
//   hides under the previous iteration's 16 MFMAs.
// Epilogue: e=exp(feat); per-column sum(e), sum(e*cap); 2 atomics/col.
// ---------------------------------------------------------------------------
__global__ __launch_bounds__(512, 4)
void esa_fused(const float* __restrict__ x, const float* __restrict__ gamma,
               const float* __restrict__ beta, const short* __restrict__ W1p,
               const short* __restrict__ W12p, const float* __restrict__ b1,
               const float* __restrict__ b12, const int4* __restrict__ entries,
               float* __restrict__ num, float* __restrict__ den) {
    __shared__ short ylds[64 * 512];   // 65,536 B exactly -> 2 blocks/CU
    const int4 e = entries[blockIdx.x];
    const int bat = e.x, start = e.y, valid = e.z;
    if (valid <= 0) return;

    const int tid = threadIdx.x;
    const int wave = tid >> 6;          // 0..7
    const int lane = tid & 63;
    const int quad = lane >> 4;
    const int l16 = lane & 15;

    // ---- Phase 1: LayerNorm, rows wave*8..+7, lane owns 8 cols. Branch-free.
    const float4 g0 = *(const float4*)(gamma + lane * 8);
    const float4 g1 = *(const float4*)(gamma + lane * 8 + 4);
    const float4 be0 = *(const float4*)(beta + lane * 8);
    const float4 be1 = *(const float4*)(beta + lane * 8 + 4);

#pragma unroll
    for (int g = 0; g < 2; ++g) {               // two ILP groups of 4 rows
        float4 ra[4], rb[4];
        float s[4], ss[4];
#pragma unroll
        for (int r = 0; r < 4; ++r) {
            const int m = wave * 8 + g * 4 + r;
            const int mc = m < valid ? m : valid - 1;   // clamp: always in-batch
            const float* xr = x + (size_t)(start + mc) * 512 + lane * 8;
            ra[r] = *(const float4*)xr;
            rb[r] = *(const float4*)(xr + 4);
        }
#pragma unroll
        for (int r = 0; r < 4; ++r) {
            s[r] = ra[r].x + ra[r].y + ra[r].z + ra[r].w +
                   rb[r].x + rb[r].y + rb[r].z + rb[r].w;
            ss[r] = ra[r].x * ra[r].x + ra[r].y * ra[r].y + ra[r].z * ra[r].z +
                    ra[r].w * ra[r].w + rb[r].x * rb[r].x + rb[r].y * rb[r].y +
                    rb[r].z * rb[r].z + rb[r].w * rb[r].w;
        }
#pragma unroll
        for (int o = 1; o <= 32; o <<= 1) {     // 4 interleaved chains
#pragma unroll
            for (int r = 0; r < 4; ++r) {
                s[r] += __shfl_xor(s[r], o);
                ss[r] += __shfl_xor(ss[r], o);
            }
        }
#pragma unroll
        for (int r = 0; r < 4; ++r) {
            const int m = wave * 8 + g * 4 + r;
            const float mu = s[r] * (1.0f / 512.0f);
            const float var = ss[r] * (1.0f / 512.0f) - mu * mu;
            const float rstd = rsqrtf(var + 1e-5f);
            short8 outv;
            outv[0] = f2bf((ra[r].x - mu) * rstd * g0.x + be0.x);
            outv[1] = f2bf((ra[r].y - mu) * rstd * g0.y + be0.y);
            outv[2] = f2bf((ra[r].z - mu) * rstd * g0.z + be0.z);
            outv[3] = f2bf((ra[r].w - mu) * rstd * g0.w + be0.w);
            outv[4] = f2bf((rb[r].x - mu) * rstd * g1.x + be1.x);
            outv[5] = f2bf((rb[r].y - mu) * rstd * g1.y + be1.y);
            outv[6] = f2bf((rb[r].z - mu) * rstd * g1.z + be1.z);
            outv[7] = f2bf((rb[r].w - mu) * rstd * g1.w + be1.w);
            // XOR swizzle: column-block lane stored at lane ^ (m&7)
            *(short8*)&ylds[m * 512 + ((lane ^ (m & 7)) * 8)] = outv;
        }
    }
    __syncthreads();

    // ---- Phase 2: dual GEMM + epilogue. Wave owns cols [wave*64, +64).
    const int xr7 = l16 & 7;
    const short* abase = ylds + l16 * 512;
    const bool full = (valid >= 64);

    for (int grp = 0; grp < 2; ++grp) {
        const int n0 = wave * 64 + grp * 32;
        const int ntile0 = n0 >> 4;           // wave*4 + grp*2
        f32x4 acc_c[2][4], acc_f[2][4];
#pragma unroll
        for (int nt = 0; nt < 2; ++nt)
#pragma unroll
            for (int mt = 0; mt < 4; ++mt) {
                acc_c[nt][mt] = (f32x4)0.0f;
                acc_f[nt][mt] = (f32x4)0.0f;
            }
        // packed B bases: lane-contiguous 1KB per (ntile, k0) chunk
        const short* w1t0 = W1p + (size_t)ntile0 * 8192 + lane * 8;
        const short* w1t1 = w1t0 + 8192;
        const short* w2t0 = W12p + (size_t)ntile0 * 8192 + lane * 8;
        const short* w2t1 = w2t0 + 8192;

        // pipeline prologue: b-frags for k0 = 0
        short8 b10 = *(const short8*)(w1t0);
        short8 b11 = *(const short8*)(w1t1);
        short8 b20 = *(const short8*)(w2t0);
        short8 b21 = *(const short8*)(w2t1);

#pragma unroll 2
        for (int k0 = 0; k0 < 16; ++k0) {
            // issue NEXT k0's B-frag loads first: their ~250-300cy L2 latency
            // hides under this iteration's 16 MFMAs. (k0=15 re-reads k0=0,
            // L1-hot, harmless.)
            const int kn = (k0 + 1) & 15;
            const short8 nb10 = *(const short8*)(w1t0 + kn * 512);
            const short8 nb11 = *(const short8*)(w1t1 + kn * 512);
            const short8 nb20 = *(const short8*)(w2t0 + kn * 512);
            const short8 nb21 = *(const short8*)(w2t1 + kn * 512);

            // swizzled A-frag address: column block (4k0+quad) ^ (l16&7)
            const int blk = ((k0 << 2) | quad) ^ xr7;
            const short* ap = abase + blk * 8;

            __builtin_amdgcn_s_setprio(1);
#pragma unroll
            for (int mt = 0; mt < 4; ++mt) {
                // A-frag streamed per-mt: live range 1-2 frags, frees the
                // registers that pay for the B double-buffer.
                const short8 afr = *(const short8*)(ap + mt * 16 * 512);
                acc_c[0][mt] = __builtin_amdgcn_mfma_f32_16x16x32_bf16(
                    afr, b10, acc_c[0][mt], 0, 0, 0);
                acc_c[1][mt] = __builtin_amdgcn_mfma_f32_16x16x32_bf16(
                    afr, b11, acc_c[1][mt], 0, 0, 0);
                acc_f[0][mt] = __builtin_amdgcn_mfma_f32_16x16x32_bf16(
                    afr, b20, acc_f[0][mt], 0, 0, 0);
                acc_f[1][mt] = __builtin_amdgcn_mfma_f32_16x16x32_bf16(
                    afr, b21, acc_f[1][mt], 0, 0, 0);
            }
            __builtin_amdgcn_s_setprio(0);
            b10 = nb10; b11 = nb11; b20 = nb20; b21 = nb21;
        }
        // Epilogue: C/D layout col=lane&15, row=quad*4+reg (m89-verified)
#pragma unroll
        for (int nt = 0; nt < 2; ++nt) {
            const int n = n0 + nt * 16 + l16;
            const float bb1 = b1[n];
            const float bb2 = b12[n];
            float se = 0.0f, sec = 0.0f;
            if (full) {
                // wave-uniform fast path: every row valid, no compares
#pragma unroll
                for (int mt = 0; mt < 4; ++mt) {
#pragma unroll
                    for (int r2 = 0; r2 < 4; ++r2) {
                        const float cap = acc_c[nt][mt][r2] + bb1;
                        const float ev = __expf(acc_f[nt][mt][r2] + bb2);
                        se += ev;
                        sec += ev * cap;
                    }
                }
            } else {
#pragma unroll
                for (int mt = 0; mt < 4; ++mt) {
#pragma unroll
                    for (int r2 = 0; r2 < 4; ++r2) {
                        const int m = mt * 16 + quad * 4 + r2;
                        if (m < valid) {
                            const float cap = acc_c[nt][mt][r2] + bb1;
                            const float ev = __expf(acc_f[nt][mt][r2] + bb2);
                            se += ev;
                            sec += ev * cap;
                        }
                    }
                }
            }
            se += __shfl_xor(se, 16);
            se += __shfl_xor(se, 32);
            sec += __shfl_xor(sec, 16);
            sec += __shfl_xor(sec, 32);
            if (quad == 0) atomicAdd(&den[(size_t)bat * 512 + n], se);
            else if (quad == 1) atomicAdd(&num[(size_t)bat * 512 + n], sec);
        }
    }
}

__global__ __launch_bounds__(256)
void esa_finalize(const float* __restrict__ num, const float* __restrict__ den,
                  float* __restrict__ out, int n) {
    const int i = blockIdx.x * 256 + threadIdx.x;
    if (i < n) {
        const float d = den[i];
        out[i] = d > 0.0f ? num[i] / d : 0.0f;
    }
}

extern "C" void kernel_launch(void* const* d_in, const int* in_sizes, int n_in,
                              void* d_out, int out_size, void* d_ws, size_t ws_size,
                              hipStream_t stream) {
    const float* x = (const float*)d_in[0];
    const int* db = (const int*)d_in[1];
    // d_in[2] = max_nodes (unused: chunking derived from actual counts)
    const float* gamma = (const float*)d_in[3];
    const float* beta = (const float*)d_in[4];
    const float* W1 = (const float*)d_in[5];
    const float* b1 = (const float*)d_in[6];
    const float* W2 = (const float*)d_in[7];
    const float* b2 = (const float*)d_in[8];
    float* out = (float*)d_out;

    const int C = in_sizes[3];        // 512
    const int D = in_sizes[6];        // 512
    const int T = in_sizes[0] / C;    // 131072
    const int B = out_size / D;       // 128
    const int maxent = B + (T + 63) / 64;   // 2176

    char* ws = (char*)d_ws;
    short* W1p = (short*)(ws);                      // 512 KB packed
    short* W12p = (short*)(ws + 524288);            // 512 KB packed
    float* b12 = (float*)(ws + 1048576);            // 2 KB
    int4* entries = (int4*)(ws + 1050624);          // maxent*16
    size_t numoff = (1050624 + (size_t)maxent * 16 + 255) & ~(size_t)255;
    float* num = (float*)(ws + numoff);             // B*D*4
    float* den = (float*)(ws + numoff + (size_t)B * D * 4);

    esa_prep_all<<<PREP_GRID, 512, 0, stream>>>(W1, W2, b1, b2, db, T, B,
                                                W1p, W12p, b12, entries, maxent,
                                                num);
    esa_fused<<<maxent, 512, 0, stream>>>(x, gamma, beta, W1p, W12p, b1, b12,
                                          entries, num, den);
    esa_finalize<<<(B * D + 255) / 256, 256, 0, stream>>>(num, den, out, B * D);
}